// Round 3
// baseline (403.218 us; speedup 1.0000x reference)
//
#include <hip/hip_runtime.h>
#include <hip/hip_fp16.h>
#include <stdint.h>

// Shapes (fixed by the reference):
//   tract a: x (8192, 4096), W/M (1024, 4096), 64 conns/row
//   tract b: x (8192, 4096), W/M ( 512, 4096), 64 conns/row
//   tract c: x (8192, 2048), W/M ( 512, 2048), 32 conns/row
//   out (8192, 2048) = concat(a:1024, b:512, c:512)
//
// Round-3 structure: per-tract blocks, 8 rows/block, 512 threads.
// LDS = 16 B/src (4x half2 = rows 0..7) = 64 KB for A/B -> 2 blocks/CU but
// 8 waves/block = 16 waves/CU (50% occ). Each table entry feeds 8 MACs via
// one ds_read_b128 + 8 v_fma_mix (f32 accumulation, no accuracy change).

#define BS_TOTAL 8192
#define SRC_A 4096
#define SRC_B 4096
#define SRC_C 2048
#define DST_A 1024
#define DST_B 512
#define DST_C 512
#define K_A 64
#define K_B 64
#define K_C 32
#define OUT_DIM 2048
#define ROWS 8
#define THREADS 512

#define NBLK (BS_TOTAL / ROWS)                // 1024 per tract
#define LDS_BYTES (SRC_A * 16)                // 64 KB (A/B full; C uses half)

typedef float f32x4 __attribute__((ext_vector_type(4)));

// LDS layout: per src index one 16-byte record:
//   { half2{r0,r1}, half2{r2,r3}, half2{r4,r5}, half2{r6,r7} }
// Table entry: (byte_off << 16) | fp16_bits(w), byte_off = src_idx*16
// (max 65520, fits u16). Table layout [K/4][DST][4] uint32 == [K/4][DST]
// uint4 -> one coalesced dwordx4 per dst fetches 4 k-entries.

// ---------------------------------------------------------------------------
// Kernel 1: one block per dst row. Scan the mask (float4), collect nonzero
// indices, counting-sort by LDS bank-GROUP (idx & 7: each src owns 16 B = 4
// of the 32 banks -> 8 groups), rotate the k-sequence per dst so a wave's 64
// lanes spread across the 8 groups at every k step (8 lanes/group = the b128
// minimum cadence).
// ---------------------------------------------------------------------------
__global__ __launch_bounds__(256) void compress_kernel(
    const float* __restrict__ w_a, const float* __restrict__ m_a,
    const float* __restrict__ w_b, const float* __restrict__ m_b,
    const float* __restrict__ w_c, const float* __restrict__ m_c,
    unsigned* __restrict__ pa, unsigned* __restrict__ pb,
    unsigned* __restrict__ pc) {
    __shared__ int s_cnt;
    __shared__ int s_idx[64];
    __shared__ int s_bankcnt[8];
    __shared__ int s_bankoff[8];
    __shared__ unsigned s_sorted[64];

    const int blk = blockIdx.x;
    const int t = threadIdx.x;

    const float *w, *m;
    unsigned* p;
    int dst, src_n, K, DST;
    if (blk < DST_A) {
        w = w_a; m = m_a; p = pa; dst = blk;
        src_n = SRC_A; K = K_A; DST = DST_A;
    } else if (blk < DST_A + DST_B) {
        w = w_b; m = m_b; p = pb; dst = blk - DST_A;
        src_n = SRC_B; K = K_B; DST = DST_B;
    } else {
        w = w_c; m = m_c; p = pc; dst = blk - DST_A - DST_B;
        src_n = SRC_C; K = K_C; DST = DST_C;
    }

    if (t == 0) s_cnt = 0;
    if (t < 8) s_bankcnt[t] = 0;
    __syncthreads();

    const float* mrow = m + (size_t)dst * src_n;
    const float* wrow = w + (size_t)dst * src_n;
    const f32x4* m4 = (const f32x4*)mrow;
    const int nq = src_n >> 10;              // float4s per thread: 4 or 2
    for (int i = 0; i < nq; ++i) {
        int q = t + (i << 8);
        f32x4 mv = m4[q];
#pragma unroll
        for (int j = 0; j < 4; ++j) {
            if (mv[j] != 0.0f) {
                int pos = atomicAdd(&s_cnt, 1);
                if (pos < 64) s_idx[pos] = 4 * q + j;
            }
        }
    }
    __syncthreads();
    int cnt = s_cnt;
    if (cnt > K) cnt = K;

    // histogram by bank-group
    if (t < cnt) atomicAdd(&s_bankcnt[s_idx[t] & 7], 1);
    __syncthreads();
    if (t == 0) {
        int acc = 0;
        for (int b = 0; b < 8; ++b) {
            s_bankoff[b] = acc;
            acc += s_bankcnt[b];
        }
    }
    __syncthreads();
    // scatter sorted-by-group, packed with PRE-SCALED byte offset (idx*16)
    if (t < cnt) {
        int idx = s_idx[t];
        int j = atomicAdd(&s_bankoff[idx & 7], 1);
        float wv = wrow[idx] * mrow[idx];
        unsigned hb = (unsigned)__half_as_ushort(__float2half(wv));
        s_sorted[j] = ((unsigned)(idx << 4) << 16) | hb;
    }
    __syncthreads();
    // pad (defensive; masks have exactly K nonzeros). off=0,w=0 -> adds 0.
    if (t >= cnt && t < K) s_sorted[t] = 0u;
    __syncthreads();

    // rotate and store into [K/4][DST][4]; sum order is irrelevant, only the
    // per-k-step bank-group spread across a wave's 64 consecutive dst matters.
    if (t < K) {
        int rot = (K == 64) ? ((dst & 7) << 3) : ((dst & 7) << 2);
        unsigned v = s_sorted[(t + rot) & (K - 1)];
        p[(((t >> 2) * DST) + dst) * 4 + (t & 3)] = v;
    }
}

// ---------------------------------------------------------------------------
// Kernel 2: per-tract blocks, 8 rows each, 512 threads. Stage 8 rows as fp16
// in LDS (16 B per src), then each thread computes NOUT dst columns for all
// 8 rows: uint4 table load (4 k-entries) -> 4x { ds_read_b128 + 8 fma_mix }.
// ---------------------------------------------------------------------------

// one entry -> 8 MACs (rows 0..7). fmaf(w, cvt(f16), acc) -> v_fma_mix_f32.
#define PROC(u) {                                                            \
        const uint4 xv = *(const uint4*)((const char*)xs + ((u) >> 16));     \
        float w = __half2float(__ushort_as_half((unsigned short)((u) & 0xffffu))); \
        const __half2 h01 = *(const __half2*)&xv.x;                          \
        const __half2 h23 = *(const __half2*)&xv.y;                          \
        const __half2 h45 = *(const __half2*)&xv.z;                          \
        const __half2 h67 = *(const __half2*)&xv.w;                          \
        acc0 = fmaf(w, __low2float(h01), acc0);                              \
        acc1 = fmaf(w, __high2float(h01), acc1);                             \
        acc2 = fmaf(w, __low2float(h23), acc2);                              \
        acc3 = fmaf(w, __high2float(h23), acc3);                             \
        acc4 = fmaf(w, __low2float(h45), acc4);                              \
        acc5 = fmaf(w, __high2float(h45), acc5);                             \
        acc6 = fmaf(w, __low2float(h67), acc6);                              \
        acc7 = fmaf(w, __high2float(h67), acc7); }

template <int SRCN, int KQ, int DSTN, int NOUT>
__device__ __forceinline__ void do_tract(
    const float* __restrict__ xsrc, const uint4* __restrict__ tab,
    float* __restrict__ outb,   // out + r0*OUT_DIM + tract col offset
    size_t r0, int t, unsigned* xs) {
    // ---- staging: SRCN/4 quads; quad q covers srcs 4q..4q+3 of 8 rows ----
    const f32x4* s0 = (const f32x4*)(xsrc + (r0 + 0) * SRCN);
    const f32x4* s1 = (const f32x4*)(xsrc + (r0 + 1) * SRCN);
    const f32x4* s2 = (const f32x4*)(xsrc + (r0 + 2) * SRCN);
    const f32x4* s3 = (const f32x4*)(xsrc + (r0 + 3) * SRCN);
    const f32x4* s4 = (const f32x4*)(xsrc + (r0 + 4) * SRCN);
    const f32x4* s5 = (const f32x4*)(xsrc + (r0 + 5) * SRCN);
    const f32x4* s6 = (const f32x4*)(xsrc + (r0 + 6) * SRCN);
    const f32x4* s7 = (const f32x4*)(xsrc + (r0 + 7) * SRCN);
    uint4* xs4 = (uint4*)xs;

#pragma unroll
    for (int i = 0; i < (SRCN >> 11); ++i) {
        int q = t + (i << 9);                // src-quad index
        f32x4 v0 = s0[q];
        f32x4 v1 = s1[q];
        f32x4 v2 = s2[q];
        f32x4 v3 = s3[q];
        f32x4 v4 = s4[q];
        f32x4 v5 = s5[q];
        f32x4 v6 = s6[q];
        f32x4 v7 = s7[q];
        __half2 h;
        uint4 rec;
#pragma unroll
        for (int j = 0; j < 4; ++j) {
            h = __floats2half2_rn(v0[j], v1[j]); rec.x = *(unsigned*)&h;
            h = __floats2half2_rn(v2[j], v3[j]); rec.y = *(unsigned*)&h;
            h = __floats2half2_rn(v4[j], v5[j]); rec.z = *(unsigned*)&h;
            h = __floats2half2_rn(v6[j], v7[j]); rec.w = *(unsigned*)&h;
            xs4[4 * q + j] = rec;
        }
    }
    __syncthreads();

    float* o0 = outb;

#pragma unroll 1
    for (int o = 0; o < NOUT; ++o) {
        int dst = t + (o << 9);
        float acc0 = 0.0f, acc1 = 0.0f, acc2 = 0.0f, acc3 = 0.0f;
        float acc4 = 0.0f, acc5 = 0.0f, acc6 = 0.0f, acc7 = 0.0f;
#pragma unroll 4
        for (int k4 = 0; k4 < KQ; ++k4) {
            uint4 e = tab[k4 * DSTN + dst];
            PROC(e.x) PROC(e.y) PROC(e.z) PROC(e.w)
        }
        __builtin_nontemporal_store(acc0, o0 + 0 * OUT_DIM + dst);
        __builtin_nontemporal_store(acc1, o0 + 1 * OUT_DIM + dst);
        __builtin_nontemporal_store(acc2, o0 + 2 * OUT_DIM + dst);
        __builtin_nontemporal_store(acc3, o0 + 3 * OUT_DIM + dst);
        __builtin_nontemporal_store(acc4, o0 + 4 * OUT_DIM + dst);
        __builtin_nontemporal_store(acc5, o0 + 5 * OUT_DIM + dst);
        __builtin_nontemporal_store(acc6, o0 + 6 * OUT_DIM + dst);
        __builtin_nontemporal_store(acc7, o0 + 7 * OUT_DIM + dst);
    }
}

__global__ __launch_bounds__(THREADS, 4) void tract_kernel(
    const float* __restrict__ x_a, const float* __restrict__ x_b,
    const float* __restrict__ x_c,
    const unsigned* __restrict__ pa, const unsigned* __restrict__ pb,
    const unsigned* __restrict__ pc,
    float* __restrict__ out) {
    extern __shared__ unsigned xs[];
    const int t = threadIdx.x;
    const int blk = blockIdx.x;

    if (blk < NBLK) {
        size_t r0 = (size_t)blk * ROWS;
        do_tract<SRC_A, K_A / 4, DST_A, 2>(
            x_a, (const uint4*)pa, out + r0 * OUT_DIM, r0, t, xs);
    } else if (blk < 2 * NBLK) {
        size_t r0 = (size_t)(blk - NBLK) * ROWS;
        do_tract<SRC_B, K_B / 4, DST_B, 1>(
            x_b, (const uint4*)pb, out + r0 * OUT_DIM + DST_A, r0, t, xs);
    } else {
        size_t r0 = (size_t)(blk - 2 * NBLK) * ROWS;
        do_tract<SRC_C, K_C / 4, DST_C, 1>(
            x_c, (const uint4*)pc, out + r0 * OUT_DIM + DST_A + DST_B, r0, t, xs);
    }
}

// ---------------------------------------------------------------------------
extern "C" void kernel_launch(void* const* d_in, const int* in_sizes, int n_in,
                              void* d_out, int out_size, void* d_ws, size_t ws_size,
                              hipStream_t stream) {
    // setup_inputs() dict order: x_a, w_a, m_a, x_b, w_b, m_b, x_c, w_c, m_c
    const float* x_a = (const float*)d_in[0];
    const float* w_a = (const float*)d_in[1];
    const float* m_a = (const float*)d_in[2];
    const float* x_b = (const float*)d_in[3];
    const float* w_b = (const float*)d_in[4];
    const float* m_b = (const float*)d_in[5];
    const float* x_c = (const float*)d_in[6];
    const float* w_c = (const float*)d_in[7];
    const float* m_c = (const float*)d_in[8];
    float* out = (float*)d_out;

    // Workspace: packed tables (uint32 = byteoff<<16 | fp16 w), [K/4][DST][4].
    //   pa: 64*1024*4 = 262144 B, pb: 64*512*4 = 131072 B, pc: 32*512*4 = 65536 B
    char* ws = (char*)d_ws;
    unsigned* pa = (unsigned*)(ws);
    unsigned* pb = (unsigned*)(ws + 262144);
    unsigned* pc = (unsigned*)(ws + 262144 + 131072);

    static bool configured = false;
    if (!configured) {
        hipFuncSetAttribute(reinterpret_cast<const void*>(&tract_kernel),
                            hipFuncAttributeMaxDynamicSharedMemorySize, LDS_BYTES);
        configured = true;
    }

    compress_kernel<<<DST_A + DST_B + DST_C, 256, 0, stream>>>(
        w_a, m_a, w_b, m_b, w_c, m_c, pa, pb, pc);
    tract_kernel<<<3 * NBLK, THREADS, LDS_BYTES, stream>>>(
        x_a, x_b, x_c, pa, pb, pc, out);
}

// Round 5
// 389.924 us; speedup vs baseline: 1.0341x; 1.0341x over previous
//
#include <hip/hip_runtime.h>
#include <hip/hip_fp16.h>
#include <stdint.h>

// Shapes (fixed by the reference):
//   tract a: x (8192, 4096), W/M (1024, 4096), 64 conns/row
//   tract b: x (8192, 4096), W/M ( 512, 4096), 64 conns/row
//   tract c: x (8192, 2048), W/M ( 512, 2048), 32 conns/row
//   out (8192, 2048) = concat(a:1024, b:512, c:512)
//
// Round-5 = round-4 with the swizzle parity bug fixed:
//   odd uint4 slot of a quad lives at up0 ^ 1 (NOT up0 + 1) — the XOR value
//   x = (u0>>3)&7 can be odd, making up0 odd. Round-4 wrote xs4[up0+1],
//   clobbering a foreign slot and leaving its own uninitialized -> NaN.
//
// Design (from round 4):
//  * Round-2 skeleton: per-tract blocks, 4 rows, 256 threads, 32 KB LDS
//    (5 blocks/CU) — best measured baseline (131 us).
//  * XOR-swizzled LDS placement kills the deterministic staging-write bank
//    conflict; gather addresses are table-driven so the swizzle is baked into
//    stored byte offsets and the read bank-sort is re-keyed to match.
//  * Pre-scaled byte offsets in table entries (no per-entry shift).
//  * Dual-output interleave: each thread works dst and dst+256 at once
//    (2 table loads + 2 gather chains in flight -> 2x MLP when latency-bound).

#define BS_TOTAL 8192
#define SRC_A 4096
#define SRC_B 4096
#define SRC_C 2048
#define DST_A 1024
#define DST_B 512
#define DST_C 512
#define K_A 64
#define K_B 64
#define K_C 32
#define OUT_DIM 2048
#define ROWS 4
#define NBLK (BS_TOTAL / ROWS)                // 2048 blocks per tract
#define LDS_BYTES (SRC_A * 8)                 // 32 KB (A/B full; C uses half)

typedef float f32x4 __attribute__((ext_vector_type(4)));

// LDS layout: per src index one 8-byte "pair": {half2{r0,r1}, half2{r2,r3}}.
// Pairs are packed 2-per-uint4; uint4 slot u is PLACED at physical slot
//   u' = u ^ ((u >> 3) & 7)
// so linear staging writes spread uniformly over the 8 bank-groups.
// Table entry: (byte_off << 16) | fp16_bits(w), byte_off = u'*16 + (idx&1)*8
// (max 32760, fits u16). Table layout [K/4][DST][4] uint32 == [K/4][DST]
// uint4 -> one coalesced dwordx4 per dst fetches 4 k-entries.

// ---------------------------------------------------------------------------
// Kernel 1: one block per dst row. Scan the mask (float4), collect nonzero
// indices, counting-sort by POST-SWIZZLE LDS bank-pair (16 keys), rotate the
// k-sequence per dst so a wave's 64 lanes spread across the 16 bank-pairs at
// every k step (4 lanes/pair = the b64 conflict-free cadence).
// ---------------------------------------------------------------------------
__global__ __launch_bounds__(256) void compress_kernel(
    const float* __restrict__ w_a, const float* __restrict__ m_a,
    const float* __restrict__ w_b, const float* __restrict__ m_b,
    const float* __restrict__ w_c, const float* __restrict__ m_c,
    unsigned* __restrict__ pa, unsigned* __restrict__ pb,
    unsigned* __restrict__ pc) {
    __shared__ int s_cnt;
    __shared__ int s_idx[64];
    __shared__ int s_bankcnt[16];
    __shared__ int s_bankoff[16];
    __shared__ unsigned s_sorted[64];

    const int blk = blockIdx.x;
    const int t = threadIdx.x;

    const float *w, *m;
    unsigned* p;
    int dst, src_n, K, DST;
    if (blk < DST_A) {
        w = w_a; m = m_a; p = pa; dst = blk;
        src_n = SRC_A; K = K_A; DST = DST_A;
    } else if (blk < DST_A + DST_B) {
        w = w_b; m = m_b; p = pb; dst = blk - DST_A;
        src_n = SRC_B; K = K_B; DST = DST_B;
    } else {
        w = w_c; m = m_c; p = pc; dst = blk - DST_A - DST_B;
        src_n = SRC_C; K = K_C; DST = DST_C;
    }

    if (t == 0) s_cnt = 0;
    if (t < 16) s_bankcnt[t] = 0;
    __syncthreads();

    const float* mrow = m + (size_t)dst * src_n;
    const float* wrow = w + (size_t)dst * src_n;
    const f32x4* m4 = (const f32x4*)mrow;
    const int nq = src_n >> 10;              // float4s per thread: 4 or 2
    for (int i = 0; i < nq; ++i) {
        int q = t + (i << 8);
        f32x4 mv = m4[q];
#pragma unroll
        for (int j = 0; j < 4; ++j) {
            if (mv[j] != 0.0f) {
                int pos = atomicAdd(&s_cnt, 1);
                if (pos < 64) s_idx[pos] = 4 * q + j;
            }
        }
    }
    __syncthreads();
    int cnt = s_cnt;
    if (cnt > K) cnt = K;

    // histogram by post-swizzle bank-pair
    if (t < cnt) {
        int idx = s_idx[t];
        unsigned u = (unsigned)idx >> 1;
        unsigned up = u ^ ((u >> 3) & 7u);
        int key = (int)(((up & 7u) << 1) | ((unsigned)idx & 1u));
        atomicAdd(&s_bankcnt[key], 1);
    }
    __syncthreads();
    if (t == 0) {
        int acc = 0;
        for (int b = 0; b < 16; ++b) {
            s_bankoff[b] = acc;
            acc += s_bankcnt[b];
        }
    }
    __syncthreads();
    // scatter sorted-by-bank-pair, packed with PRE-SCALED swizzled byte off
    if (t < cnt) {
        int idx = s_idx[t];
        unsigned u = (unsigned)idx >> 1;
        unsigned up = u ^ ((u >> 3) & 7u);
        unsigned boff = (up << 4) | (((unsigned)idx & 1u) << 3);
        int key = (int)(((up & 7u) << 1) | ((unsigned)idx & 1u));
        int j = atomicAdd(&s_bankoff[key], 1);
        float wv = wrow[idx] * mrow[idx];
        unsigned hb = (unsigned)__half_as_ushort(__float2half(wv));
        s_sorted[j] = (boff << 16) | hb;
    }
    __syncthreads();
    // pad (defensive; masks have exactly K nonzeros). off=0,w=0 -> adds 0.
    if (t >= cnt && t < K) s_sorted[t] = 0u;
    __syncthreads();

    // rotate and store into [K/4][DST][4]; sum order is irrelevant, only the
    // per-k-step bank-pair spread across a wave's 64 consecutive dst matters.
    if (t < K) {
        int rot = (K == 64) ? ((dst & 15) << 2) : ((dst & 15) << 1);
        unsigned v = s_sorted[(t + rot) & (K - 1)];
        p[(((t >> 2) * DST) + dst) * 4 + (t & 3)] = v;
    }
}

// ---------------------------------------------------------------------------
// Kernel 2: per-tract blocks, 4 rows each, 256 threads. Stage 4 rows as fp16
// pairs in swizzled LDS, then each thread computes dst and dst+256 together:
// 2x uint4 table loads (4 k-entries each) -> 8x { ds_read_b64 + 4 fma }.
// ---------------------------------------------------------------------------

#define PROC(u, A0, A1, A2, A3) {                                            \
        const uint2 xv = *(const uint2*)((const char*)xs + ((u) >> 16));     \
        const float w = __half2float(__ushort_as_half((unsigned short)((u) & 0xffffu))); \
        const __half2 hlo = *(const __half2*)&xv.x;                          \
        const __half2 hhi = *(const __half2*)&xv.y;                          \
        A0 = fmaf(w, __low2float(hlo), A0);                                  \
        A1 = fmaf(w, __high2float(hlo), A1);                                 \
        A2 = fmaf(w, __low2float(hhi), A2);                                  \
        A3 = fmaf(w, __high2float(hhi), A3); }

template <int SRCN, int KQ, int DSTN, int NPAIR>
__device__ __forceinline__ void do_tract(
    const float* __restrict__ xsrc, const uint4* __restrict__ tab,
    float* __restrict__ outb,   // out + r0*OUT_DIM + tract col offset
    size_t r0, int t, unsigned* xs) {
    // ---- staging: SRCN/4 quads; quad q covers srcs 4q..4q+3 of 4 rows ----
    const f32x4* s0 = (const f32x4*)(xsrc + (r0 + 0) * SRCN);
    const f32x4* s1 = (const f32x4*)(xsrc + (r0 + 1) * SRCN);
    const f32x4* s2 = (const f32x4*)(xsrc + (r0 + 2) * SRCN);
    const f32x4* s3 = (const f32x4*)(xsrc + (r0 + 3) * SRCN);
    uint4* xs4 = (uint4*)xs;

#pragma unroll
    for (int i = 0; i < (SRCN >> 10); ++i) {
        int q = t + (i << 8);
        f32x4 v0 = s0[q];
        f32x4 v1 = s1[q];
        f32x4 v2 = s2[q];
        f32x4 v3 = s3[q];
        uint4 w0, w1;
        __half2 h;
        h = __floats2half2_rn(v0.x, v1.x); w0.x = *(unsigned*)&h;
        h = __floats2half2_rn(v2.x, v3.x); w0.y = *(unsigned*)&h;
        h = __floats2half2_rn(v0.y, v1.y); w0.z = *(unsigned*)&h;
        h = __floats2half2_rn(v2.y, v3.y); w0.w = *(unsigned*)&h;
        h = __floats2half2_rn(v0.z, v1.z); w1.x = *(unsigned*)&h;
        h = __floats2half2_rn(v2.z, v3.z); w1.y = *(unsigned*)&h;
        h = __floats2half2_rn(v0.w, v1.w); w1.z = *(unsigned*)&h;
        h = __floats2half2_rn(v2.w, v3.w); w1.w = *(unsigned*)&h;
        unsigned u0 = (unsigned)(2 * q);              // even slot of the quad
        unsigned up0 = u0 ^ ((u0 >> 3) & 7u);         // swizzled even slot
        xs4[up0]     = w0;
        xs4[up0 ^ 1] = w1;   // odd slot: (u0|1)^x == (u0^x)^1, NOT up0+1
    }
    __syncthreads();

#pragma unroll 1
    for (int op = 0; op < NPAIR; ++op) {
        const int d0 = t + (op << 9);             // outputs d0 and d0+256
        float a0 = 0.f, a1 = 0.f, a2 = 0.f, a3 = 0.f;
        float b0 = 0.f, b1 = 0.f, b2 = 0.f, b3 = 0.f;
#pragma unroll 4
        for (int k4 = 0; k4 < KQ; ++k4) {
            uint4 e0 = tab[k4 * DSTN + d0];
            uint4 e1 = tab[k4 * DSTN + d0 + 256];
            PROC(e0.x, a0, a1, a2, a3)
            PROC(e1.x, b0, b1, b2, b3)
            PROC(e0.y, a0, a1, a2, a3)
            PROC(e1.y, b0, b1, b2, b3)
            PROC(e0.z, a0, a1, a2, a3)
            PROC(e1.z, b0, b1, b2, b3)
            PROC(e0.w, a0, a1, a2, a3)
            PROC(e1.w, b0, b1, b2, b3)
        }
        __builtin_nontemporal_store(a0, outb + 0 * OUT_DIM + d0);
        __builtin_nontemporal_store(a1, outb + 1 * OUT_DIM + d0);
        __builtin_nontemporal_store(a2, outb + 2 * OUT_DIM + d0);
        __builtin_nontemporal_store(a3, outb + 3 * OUT_DIM + d0);
        __builtin_nontemporal_store(b0, outb + 0 * OUT_DIM + d0 + 256);
        __builtin_nontemporal_store(b1, outb + 1 * OUT_DIM + d0 + 256);
        __builtin_nontemporal_store(b2, outb + 2 * OUT_DIM + d0 + 256);
        __builtin_nontemporal_store(b3, outb + 3 * OUT_DIM + d0 + 256);
    }
}

__global__ __launch_bounds__(256) void tract_kernel(
    const float* __restrict__ x_a, const float* __restrict__ x_b,
    const float* __restrict__ x_c,
    const unsigned* __restrict__ pa, const unsigned* __restrict__ pb,
    const unsigned* __restrict__ pc,
    float* __restrict__ out) {
    extern __shared__ unsigned xs[];
    const int t = threadIdx.x;
    const int blk = blockIdx.x;

    if (blk < NBLK) {
        size_t r0 = (size_t)blk * ROWS;
        do_tract<SRC_A, K_A / 4, DST_A, 2>(
            x_a, (const uint4*)pa, out + r0 * OUT_DIM, r0, t, xs);
    } else if (blk < 2 * NBLK) {
        size_t r0 = (size_t)(blk - NBLK) * ROWS;
        do_tract<SRC_B, K_B / 4, DST_B, 1>(
            x_b, (const uint4*)pb, out + r0 * OUT_DIM + DST_A, r0, t, xs);
    } else {
        size_t r0 = (size_t)(blk - 2 * NBLK) * ROWS;
        do_tract<SRC_C, K_C / 4, DST_C, 1>(
            x_c, (const uint4*)pc, out + r0 * OUT_DIM + DST_A + DST_B, r0, t, xs);
    }
}

// ---------------------------------------------------------------------------
extern "C" void kernel_launch(void* const* d_in, const int* in_sizes, int n_in,
                              void* d_out, int out_size, void* d_ws, size_t ws_size,
                              hipStream_t stream) {
    // setup_inputs() dict order: x_a, w_a, m_a, x_b, w_b, m_b, x_c, w_c, m_c
    const float* x_a = (const float*)d_in[0];
    const float* w_a = (const float*)d_in[1];
    const float* m_a = (const float*)d_in[2];
    const float* x_b = (const float*)d_in[3];
    const float* w_b = (const float*)d_in[4];
    const float* m_b = (const float*)d_in[5];
    const float* x_c = (const float*)d_in[6];
    const float* w_c = (const float*)d_in[7];
    const float* m_c = (const float*)d_in[8];
    float* out = (float*)d_out;

    // Workspace: packed tables (uint32 = byteoff<<16 | fp16 w), [K/4][DST][4].
    //   pa: 64*1024*4 = 262144 B, pb: 64*512*4 = 131072 B, pc: 32*512*4 = 65536 B
    char* ws = (char*)d_ws;
    unsigned* pa = (unsigned*)(ws);
    unsigned* pb = (unsigned*)(ws + 262144);
    unsigned* pc = (unsigned*)(ws + 262144 + 131072);

    compress_kernel<<<DST_A + DST_B + DST_C, 256, 0, stream>>>(
        w_a, m_a, w_b, m_b, w_c, m_c, pa, pb, pc);
    tract_kernel<<<3 * NBLK, 256, LDS_BYTES, stream>>>(
        x_a, x_b, x_c, pa, pb, pc, out);
}

// Round 6
// 385.674 us; speedup vs baseline: 1.0455x; 1.0110x over previous
//
#include <hip/hip_runtime.h>
#include <hip/hip_fp16.h>
#include <stdint.h>

// Shapes (fixed by the reference):
//   tract a: x (8192, 4096), W/M (1024, 4096), 64 conns/row
//   tract b: x (8192, 4096), W/M ( 512, 4096), 64 conns/row
//   tract c: x (8192, 2048), W/M ( 512, 2048), 32 conns/row
//   out (8192, 2048) = concat(a:1024, b:512, c:512)
//
// Round-6:
//  * FIXED-SLOT bank schedule in compress: each of the 16 bank-pairs owns
//    exactly K/16 slots; rotation by (dst&15)*CAP then gives EXACTLY 4
//    lanes/bank-pair at every gather step for aligned entries (b64
//    conflict-free). R5 counters proved conflicts live in the gather reads
//    (3.7e6 wave reads x ~4.3 extra cyc) and that sort+rotate with variable
//    run lengths does not fix them.
//  * 512-thread blocks at unchanged 32 KB LDS: 4 blocks x 8 waves = 32
//    waves/CU theoretical (R5: 5 x 4 = 20 cap, 41% measured). Same total
//    work, twice the resident waves to hide LDS/L2 latency.

#define BS_TOTAL 8192
#define SRC_A 4096
#define SRC_B 4096
#define SRC_C 2048
#define DST_A 1024
#define DST_B 512
#define DST_C 512
#define K_A 64
#define K_B 64
#define K_C 32
#define OUT_DIM 2048
#define ROWS 4
#define THREADS 512
#define NBLK (BS_TOTAL / ROWS)                // 2048 blocks per tract
#define LDS_BYTES (SRC_A * 8)                 // 32 KB (A/B full; C uses half)

typedef float f32x4 __attribute__((ext_vector_type(4)));

// LDS layout: per src index one 8-byte "pair": {half2{r0,r1}, half2{r2,r3}}.
// Pairs are packed 2-per-uint4; uint4 slot u is PLACED at physical slot
//   u' = u ^ ((u >> 3) & 7)
// so linear staging writes spread uniformly over the 8 bank-groups.
// Odd slot of a quad lives at up0 ^ 1 (parity-correct; round-5 lesson).
// Table entry: (byte_off << 16) | fp16_bits(w), byte_off = u'*16 + (idx&1)*8
// (max 32760, fits u16). Table layout [K/4][DST][4] uint32 == [K/4][DST]
// uint4 -> one coalesced dwordx4 per dst fetches 4 k-entries.

// ---------------------------------------------------------------------------
// Kernel 1: one block per dst row. Scan the mask, collect nonzero indices,
// assign each entry to a FIXED slot of its post-swizzle bank-pair (CAP=K/16
// slots per pair); overflow entries fill the empty slots of underfull pairs.
// Rotate the k-sequence by (dst&15)*CAP so a wave's 64 lanes spread exactly
// 4/bank-pair at every k step for aligned entries.
// ---------------------------------------------------------------------------
__global__ __launch_bounds__(256) void compress_kernel(
    const float* __restrict__ w_a, const float* __restrict__ m_a,
    const float* __restrict__ w_b, const float* __restrict__ m_b,
    const float* __restrict__ w_c, const float* __restrict__ m_c,
    unsigned* __restrict__ pa, unsigned* __restrict__ pb,
    unsigned* __restrict__ pc) {
    __shared__ int s_cnt;
    __shared__ int s_idx[64];
    __shared__ int s_paircnt[16];
    __shared__ int s_ovf_cnt;
    __shared__ unsigned s_ovf[64];
    __shared__ unsigned s_sorted[64];

    const int blk = blockIdx.x;
    const int t = threadIdx.x;

    const float *w, *m;
    unsigned* p;
    int dst, src_n, K, DST;
    if (blk < DST_A) {
        w = w_a; m = m_a; p = pa; dst = blk;
        src_n = SRC_A; K = K_A; DST = DST_A;
    } else if (blk < DST_A + DST_B) {
        w = w_b; m = m_b; p = pb; dst = blk - DST_A;
        src_n = SRC_B; K = K_B; DST = DST_B;
    } else {
        w = w_c; m = m_c; p = pc; dst = blk - DST_A - DST_B;
        src_n = SRC_C; K = K_C; DST = DST_C;
    }
    const int CAP = K >> 4;                   // 4 (K=64) or 2 (K=32)

    if (t == 0) { s_cnt = 0; s_ovf_cnt = 0; }
    if (t < 16) s_paircnt[t] = 0;
    if (t < 64) s_sorted[t] = 0u;             // defensive: empty slot adds 0
    __syncthreads();

    const float* mrow = m + (size_t)dst * src_n;
    const float* wrow = w + (size_t)dst * src_n;
    const f32x4* m4 = (const f32x4*)mrow;
    const int nq = src_n >> 10;               // float4s per thread: 4 or 2
    for (int i = 0; i < nq; ++i) {
        int q = t + (i << 8);
        f32x4 mv = m4[q];
#pragma unroll
        for (int j = 0; j < 4; ++j) {
            if (mv[j] != 0.0f) {
                int pos = atomicAdd(&s_cnt, 1);
                if (pos < 64) s_idx[pos] = 4 * q + j;
            }
        }
    }
    __syncthreads();
    int cnt = s_cnt;
    if (cnt > K) cnt = K;

    // pass 1: fixed-slot assignment by post-swizzle bank-pair
    if (t < cnt) {
        int idx = s_idx[t];
        unsigned u = (unsigned)idx >> 1;
        unsigned up = u ^ ((u >> 3) & 7u);
        unsigned boff = (up << 4) | (((unsigned)idx & 1u) << 3);
        int key = (int)(((up & 7u) << 1) | ((unsigned)idx & 1u));
        float wv = wrow[idx] * mrow[idx];
        unsigned hb = (unsigned)__half_as_ushort(__float2half(wv));
        unsigned packed = (boff << 16) | hb;
        int r = atomicAdd(&s_paircnt[key], 1);
        if (r < CAP) {
            s_sorted[key * CAP + r] = packed;
        } else {
            int o = atomicAdd(&s_ovf_cnt, 1);
            s_ovf[o] = packed;
        }
    }
    __syncthreads();
    // pass 2: place overflow entries into empty slots (serial, tiny)
    if (t == 0) {
        int total = s_ovf_cnt;
        int o = 0;
        for (int b = 0; b < 16 && o < total; ++b) {
            int fill = s_paircnt[b];
            if (fill > CAP) fill = CAP;
            for (int r = fill; r < CAP && o < total; ++r)
                s_sorted[b * CAP + r] = s_ovf[o++];
        }
    }
    __syncthreads();

    // rotate and store into [K/4][DST][4]; sum order is irrelevant. Slots are
    // pair-aligned, so rotation by (dst&15)*CAP keeps exactly 4 lanes on each
    // bank-pair at every k step across 64 consecutive dst.
    if (t < K) {
        int rot = (dst & 15) * CAP;
        unsigned v = s_sorted[(t + rot) & (K - 1)];
        p[(((t >> 2) * DST) + dst) * 4 + (t & 3)] = v;
    }
}

// ---------------------------------------------------------------------------
// Kernel 2: per-tract blocks, 4 rows each, 512 threads (8 waves, 32 KB LDS
// -> 4 blocks/CU = 32 waves). Stage 4 rows as fp16 pairs in swizzled LDS,
// then gather: uint4 table load (4 k-entries) -> 4x { ds_read_b64 + 4 fma }.
// Tract A: each thread computes dst t and t+512 (dual chains, 2x MLP).
// ---------------------------------------------------------------------------

#define PROC(u, A0, A1, A2, A3) {                                            \
        const uint2 xv = *(const uint2*)((const char*)xs + ((u) >> 16));     \
        const __half wh = __ushort_as_half((unsigned short)((u) & 0xffffu)); \
        const __half2 hlo = *(const __half2*)&xv.x;                          \
        const __half2 hhi = *(const __half2*)&xv.y;                          \
        A0 = fmaf(__half2float(wh), __low2float(hlo), A0);                   \
        A1 = fmaf(__half2float(wh), __high2float(hlo), A1);                  \
        A2 = fmaf(__half2float(wh), __low2float(hhi), A2);                   \
        A3 = fmaf(__half2float(wh), __high2float(hhi), A3); }

template <int SRCN, int KQ, int DSTN, bool DUAL>
__device__ __forceinline__ void do_tract(
    const float* __restrict__ xsrc, const uint4* __restrict__ tab,
    float* __restrict__ outb,   // out + r0*OUT_DIM + tract col offset
    size_t r0, int t, unsigned* xs) {
    // ---- staging: SRCN/4 quads; quad q covers srcs 4q..4q+3 of 4 rows ----
    const f32x4* s0 = (const f32x4*)(xsrc + (r0 + 0) * SRCN);
    const f32x4* s1 = (const f32x4*)(xsrc + (r0 + 1) * SRCN);
    const f32x4* s2 = (const f32x4*)(xsrc + (r0 + 2) * SRCN);
    const f32x4* s3 = (const f32x4*)(xsrc + (r0 + 3) * SRCN);
    uint4* xs4 = (uint4*)xs;

#pragma unroll
    for (int i = 0; i < (SRCN >> 11); ++i) {
        int q = t + (i << 9);                 // quad index, 512 threads
        f32x4 v0 = s0[q];
        f32x4 v1 = s1[q];
        f32x4 v2 = s2[q];
        f32x4 v3 = s3[q];
        uint4 w0, w1;
        __half2 h;
        h = __floats2half2_rn(v0.x, v1.x); w0.x = *(unsigned*)&h;
        h = __floats2half2_rn(v2.x, v3.x); w0.y = *(unsigned*)&h;
        h = __floats2half2_rn(v0.y, v1.y); w0.z = *(unsigned*)&h;
        h = __floats2half2_rn(v2.y, v3.y); w0.w = *(unsigned*)&h;
        h = __floats2half2_rn(v0.z, v1.z); w1.x = *(unsigned*)&h;
        h = __floats2half2_rn(v2.z, v3.z); w1.y = *(unsigned*)&h;
        h = __floats2half2_rn(v0.w, v1.w); w1.z = *(unsigned*)&h;
        h = __floats2half2_rn(v2.w, v3.w); w1.w = *(unsigned*)&h;
        unsigned u0 = (unsigned)(2 * q);              // even slot of the quad
        unsigned up0 = u0 ^ ((u0 >> 3) & 7u);         // swizzled even slot
        xs4[up0]     = w0;
        xs4[up0 ^ 1] = w1;   // odd slot: (u0|1)^x == (u0^x)^1
    }
    __syncthreads();

    if constexpr (DUAL) {
        float a0 = 0.f, a1 = 0.f, a2 = 0.f, a3 = 0.f;
        float b0 = 0.f, b1 = 0.f, b2 = 0.f, b3 = 0.f;
#pragma unroll 4
        for (int k4 = 0; k4 < KQ; ++k4) {
            uint4 e0 = tab[k4 * DSTN + t];
            uint4 e1 = tab[k4 * DSTN + t + 512];
            PROC(e0.x, a0, a1, a2, a3)
            PROC(e1.x, b0, b1, b2, b3)
            PROC(e0.y, a0, a1, a2, a3)
            PROC(e1.y, b0, b1, b2, b3)
            PROC(e0.z, a0, a1, a2, a3)
            PROC(e1.z, b0, b1, b2, b3)
            PROC(e0.w, a0, a1, a2, a3)
            PROC(e1.w, b0, b1, b2, b3)
        }
        __builtin_nontemporal_store(a0, outb + 0 * OUT_DIM + t);
        __builtin_nontemporal_store(a1, outb + 1 * OUT_DIM + t);
        __builtin_nontemporal_store(a2, outb + 2 * OUT_DIM + t);
        __builtin_nontemporal_store(a3, outb + 3 * OUT_DIM + t);
        __builtin_nontemporal_store(b0, outb + 0 * OUT_DIM + t + 512);
        __builtin_nontemporal_store(b1, outb + 1 * OUT_DIM + t + 512);
        __builtin_nontemporal_store(b2, outb + 2 * OUT_DIM + t + 512);
        __builtin_nontemporal_store(b3, outb + 3 * OUT_DIM + t + 512);
    } else {
        float a0 = 0.f, a1 = 0.f, a2 = 0.f, a3 = 0.f;
#pragma unroll 4
        for (int k4 = 0; k4 < KQ; ++k4) {
            uint4 e0 = tab[k4 * DSTN + t];
            PROC(e0.x, a0, a1, a2, a3)
            PROC(e0.y, a0, a1, a2, a3)
            PROC(e0.z, a0, a1, a2, a3)
            PROC(e0.w, a0, a1, a2, a3)
        }
        __builtin_nontemporal_store(a0, outb + 0 * OUT_DIM + t);
        __builtin_nontemporal_store(a1, outb + 1 * OUT_DIM + t);
        __builtin_nontemporal_store(a2, outb + 2 * OUT_DIM + t);
        __builtin_nontemporal_store(a3, outb + 3 * OUT_DIM + t);
    }
}

__global__ __launch_bounds__(THREADS) void tract_kernel(
    const float* __restrict__ x_a, const float* __restrict__ x_b,
    const float* __restrict__ x_c,
    const unsigned* __restrict__ pa, const unsigned* __restrict__ pb,
    const unsigned* __restrict__ pc,
    float* __restrict__ out) {
    extern __shared__ unsigned xs[];
    const int t = threadIdx.x;
    const int blk = blockIdx.x;

    if (blk < NBLK) {
        size_t r0 = (size_t)blk * ROWS;
        do_tract<SRC_A, K_A / 4, DST_A, true>(
            x_a, (const uint4*)pa, out + r0 * OUT_DIM, r0, t, xs);
    } else if (blk < 2 * NBLK) {
        size_t r0 = (size_t)(blk - NBLK) * ROWS;
        do_tract<SRC_B, K_B / 4, DST_B, false>(
            x_b, (const uint4*)pb, out + r0 * OUT_DIM + DST_A, r0, t, xs);
    } else {
        size_t r0 = (size_t)(blk - 2 * NBLK) * ROWS;
        do_tract<SRC_C, K_C / 4, DST_C, false>(
            x_c, (const uint4*)pc, out + r0 * OUT_DIM + DST_A + DST_B, r0, t, xs);
    }
}

// ---------------------------------------------------------------------------
extern "C" void kernel_launch(void* const* d_in, const int* in_sizes, int n_in,
                              void* d_out, int out_size, void* d_ws, size_t ws_size,
                              hipStream_t stream) {
    // setup_inputs() dict order: x_a, w_a, m_a, x_b, w_b, m_b, x_c, w_c, m_c
    const float* x_a = (const float*)d_in[0];
    const float* w_a = (const float*)d_in[1];
    const float* m_a = (const float*)d_in[2];
    const float* x_b = (const float*)d_in[3];
    const float* w_b = (const float*)d_in[4];
    const float* m_b = (const float*)d_in[5];
    const float* x_c = (const float*)d_in[6];
    const float* w_c = (const float*)d_in[7];
    const float* m_c = (const float*)d_in[8];
    float* out = (float*)d_out;

    // Workspace: packed tables (uint32 = byteoff<<16 | fp16 w), [K/4][DST][4].
    //   pa: 64*1024*4 = 262144 B, pb: 64*512*4 = 131072 B, pc: 32*512*4 = 65536 B
    char* ws = (char*)d_ws;
    unsigned* pa = (unsigned*)(ws);
    unsigned* pb = (unsigned*)(ws + 262144);
    unsigned* pc = (unsigned*)(ws + 262144 + 131072);

    compress_kernel<<<DST_A + DST_B + DST_C, 256, 0, stream>>>(
        w_a, m_a, w_b, m_b, w_c, m_c, pa, pb, pc);
    tract_kernel<<<3 * NBLK, THREADS, LDS_BYTES, stream>>>(
        x_a, x_b, x_c, pa, pb, pc, out);
}